// Round 1
// baseline (699.837 us; speedup 1.0000x reference)
//
#include <hip/hip_runtime.h>
#include <hip/hip_bf16.h>

#define FDIM 128
#define HDIM 32
#define BN_EPS 1e-5f
#define BK 256         // destination nodes per bucket
#define NBITS 8        // log2(BK)
#define CHUNK_H 4096   // edges per hist block
#define CHUNK_P 4096   // edges per partition block
#define BMAX 512       // max buckets (N <= 131072)
#define NSLICE 4       // src slices: ~1.6MB bf16 table slice -> fits per-XCD 4MB L2
#define SBINS (BK * NSLICE)
#define NPW 13         // nodes per wave in aggregate
#define WPB 4          // waves per block

// ---------- per-bucket histogram (LDS) ----------
__global__ void k_hist2(const int* __restrict__ col, int* __restrict__ bcounts, int E, int B) {
    __shared__ int h[BMAX];
    for (int i = threadIdx.x; i < B; i += 256) h[i] = 0;
    __syncthreads();
    int base = blockIdx.x * CHUNK_H;
    int end = min(base + CHUNK_H, E);
    for (int e = base + threadIdx.x; e < end; e += 256)
        atomicAdd(&h[col[e] >> NBITS], 1);
    __syncthreads();
    for (int i = threadIdx.x; i < B; i += 256)
        if (h[i]) atomicAdd(&bcounts[i], h[i]);
}

// ---------- single-block exclusive scan of bucket counts ----------
__global__ void k_bscan(const int* __restrict__ bcounts, int* __restrict__ boff,
                        int* __restrict__ bcur, int* __restrict__ noffS, int B, int E, int N) {
    __shared__ int tsum[256];
    __shared__ int wtot[4];
    const int t = threadIdx.x;
    const int per = (B + 255) / 256;
    const int b0 = t * per;
    int s = 0;
    for (int k = 0; k < per; ++k) { int i = b0 + k; if (i < B) s += bcounts[i]; }
    tsum[t] = s;
    __syncthreads();
    int lane = t & 63, w = t >> 6;
    int v = tsum[t];
    int inc = v;
    for (int off = 1; off < 64; off <<= 1) {
        int u = __shfl_up(inc, off);
        if (lane >= off) inc += u;
    }
    if (lane == 63) wtot[w] = inc;
    __syncthreads();
    int pre = 0;
    for (int k = 0; k < w; ++k) pre += wtot[k];
    int acc = pre + inc - v;  // exclusive prefix
    for (int k = 0; k < per; ++k) {
        int i = b0 + k;
        if (i < B) { boff[i] = acc; bcur[i] = acc; acc += bcounts[i]; }
    }
    if (t == 0) { boff[B] = E; noffS[(size_t)N * NSLICE] = E; }
}

// ---------- partition with LDS staging: pairs[] grouped by dst bucket, coalesced writes ----------
__global__ __launch_bounds__(256) void k_partition(const int* __restrict__ row,
                                                   const int* __restrict__ col,
                                                   int* __restrict__ bcur,
                                                   unsigned* __restrict__ pairs,
                                                   int E, int B) {
    __shared__ int h[BMAX];          // counts -> local cursors
    __shared__ int lbase[BMAX + 1];  // local exclusive scan
    __shared__ int delta[BMAX];      // global_base - local_base
    __shared__ unsigned pk[CHUNK_P]; // bucket-sorted packed pairs
    const int t = threadIdx.x;
    const int base = blockIdx.x * CHUNK_P;
    const int end = min(base + CHUNK_P, E);

    for (int i = t; i < B; i += 256) h[i] = 0;
    __syncthreads();
    for (int e = base + t; e < end; e += 256)
        atomicAdd(&h[col[e] >> NBITS], 1);
    __syncthreads();
    if (t < 64) {
        int carry = 0;
        for (int bb = 0; bb < B; bb += 64) {
            int idx = bb + t;
            int v = (idx < B) ? h[idx] : 0;
            int inc = v;
            for (int off = 1; off < 64; off <<= 1) {
                int u = __shfl_up(inc, off);
                if (t >= off) inc += u;
            }
            if (idx < B) lbase[idx] = carry + inc - v;
            carry += __shfl(inc, 63);
        }
        if (t == 0) lbase[B] = carry;
    }
    __syncthreads();
    for (int b = t; b < B; b += 256) {
        int c = h[b];
        if (c) {
            int g = atomicAdd(&bcur[b], c);
            delta[b] = g - lbase[b];
        }
    }
    __syncthreads();
    for (int b = t; b < B; b += 256) h[b] = lbase[b];
    __syncthreads();
    for (int e = base + t; e < end; e += 256) {
        int c = col[e], r = row[e];
        int lpos = atomicAdd(&h[c >> NBITS], 1);
        pk[lpos] = ((unsigned)r << NBITS) | (unsigned)(c & (BK - 1));
    }
    __syncthreads();
    const int tot = lbase[B];
    for (int i = t; i < tot; i += 256) {
        int lo = 0, hi = B - 1;
        while (lo < hi) {
            int mid = (lo + hi + 1) >> 1;
            if (lbase[mid] <= i) lo = mid; else hi = mid - 1;
        }
        pairs[delta[lo] + i] = pk[i];
    }
}

// ---------- per-bucket counting sort by (dst, src-slice) -> CSR segments noffS + dinv ----------
__global__ __launch_bounds__(1024) void k_sort(const unsigned* __restrict__ pairs,
                                               const int* __restrict__ boff,
                                               int* __restrict__ srcs, int* __restrict__ noffS,
                                               float* __restrict__ dinv, int N, float invSlice) {
    __shared__ int cnt[SBINS];
    __shared__ int cur[SBINS];
    const int bb = blockIdx.x;
    const int t = threadIdx.x;
    cnt[t] = 0;   // blockDim == SBINS == 1024
    __syncthreads();
    const int beg = boff[bb], end = boff[bb + 1];
    for (int i = beg + t; i < end; i += 1024) {
        unsigned p = pairs[i];
        int src = (int)(p >> NBITS);
        int s = (int)((float)src * invSlice); if (s > NSLICE - 1) s = NSLICE - 1;
        atomicAdd(&cnt[(((int)p & (BK - 1)) << 2) | s], 1);
    }
    __syncthreads();
    if (t < 64) {
        int carry = 0;
        for (int base = 0; base < SBINS; base += 64) {
            int v = cnt[base + t];
            int inc = v;
            for (int off = 1; off < 64; off <<= 1) {
                int u = __shfl_up(inc, off);
                if (t >= off) inc += u;
            }
            cur[base + t] = beg + carry + inc - v;
            carry += __shfl(inc, 63);
        }
    }
    __syncthreads();
    {   // bin t == local_node*(NSLICE) + slice; write segment start
        int n = bb * BK + (t >> 2);
        if (n < N) noffS[(size_t)n * NSLICE + (t & 3)] = cur[t];
    }
    if (t < BK) {
        int n = bb * BK + t;
        if (n < N) {
            int tot = cnt[(t << 2)] + cnt[(t << 2) | 1] + cnt[(t << 2) | 2] + cnt[(t << 2) | 3];
            dinv[n] = rsqrtf((float)(tot + 1));  // +1 self-loop
        }
    }
    __syncthreads();
    for (int i = beg + t; i < end; i += 1024) {
        unsigned p = pairs[i];
        int src = (int)(p >> NBITS);
        int s = (int)((float)src * invSlice); if (s > NSLICE - 1) s = NSLICE - 1;
        int pos = atomicAdd(&cur[(((int)p & (BK - 1)) << 2) | s], 1);
        srcs[pos] = src;
    }
}

// ---------- GEMM: Y[n,32] = bf16(dinv[n]*(X[n,K]@W[K,32])); optional fused BN+ReLU on X ----------
template <int K, bool APPLY_BN>
__global__ void k_gemm(const float* __restrict__ X, const float* __restrict__ W,
                       const float* __restrict__ dinv, __hip_bfloat16* __restrict__ Y, int n,
                       const float* __restrict__ stats, const float* __restrict__ gamma,
                       const float* __restrict__ beta, float invN) {
    __shared__ __align__(16) float Ws[K * HDIM];
    __shared__ __align__(16) float Xs[8 * K];
    __shared__ float bnsc[K], bnsh[K];
    const int tid = threadIdx.x;
    const int row0 = blockIdx.x * 8;

    if (APPLY_BN) {
        if (tid < K) {
            float mean = stats[tid] * invN;
            float var = stats[K + tid] * invN - mean * mean;
            float sc = gamma[tid] * rsqrtf(var + BN_EPS);
            bnsc[tid] = sc;
            bnsh[tid] = beta[tid] - mean * sc;
        }
        __syncthreads();
    }
    for (int i = tid * 4; i < K * HDIM; i += 1024) {
        *(float4*)&Ws[i] = *(const float4*)&W[i];
    }
    for (int i = tid * 4; i < 8 * K; i += 1024) {
        int r = i / K, k = i % K;
        int gr = row0 + r;
        float4 v = make_float4(0.f, 0.f, 0.f, 0.f);
        if (gr < n) v = *(const float4*)&X[(size_t)gr * K + k];
        if (APPLY_BN) {
            v.x = fmaxf(v.x * bnsc[k]     + bnsh[k],     0.f);
            v.y = fmaxf(v.y * bnsc[k + 1] + bnsh[k + 1], 0.f);
            v.z = fmaxf(v.z * bnsc[k + 2] + bnsh[k + 2], 0.f);
            v.w = fmaxf(v.w * bnsc[k + 3] + bnsh[k + 3], 0.f);
        }
        *(float4*)&Xs[i] = v;
    }
    __syncthreads();
    const int r = tid >> 5, c = tid & 31;
    const int grow = row0 + r;
    if (grow < n) {
        float acc = 0.f;
#pragma unroll
        for (int k = 0; k < K; ++k) acc += Xs[r * K + k] * Ws[k * HDIM + c];
        Y[(size_t)grow * HDIM + c] = __float2bfloat16(dinv[grow] * acc);
    }
}

// bf16 pair unpack via bit ops (no cvt)
__device__ __forceinline__ float blo(unsigned u) { return __uint_as_float(u << 16); }
__device__ __forceinline__ float bhi(unsigned u) { return __uint_as_float(u & 0xffff0000u); }

// ---------- slice-phased gather-aggregate ----------
// Edges sorted by (dst, src-slice). All resident waves process slice s before slice s+1,
// so per-XCD L2 only needs the active ~1.6MB slice of the 6.4MB bf16 table -> gathers hit L2.
// Per-node partials live in LDS (part[w][i][32]); 8 lanes (1 oct) per row, uint2/lane = 64B row/oct.
__global__ __launch_bounds__(256) void k_aggregate(const uint2* __restrict__ hp8,
                                                   const float* __restrict__ dinv,
                                                   const int* __restrict__ noffS,
                                                   const int* __restrict__ srcs,
                                                   const float* __restrict__ bias,
                                                   float* __restrict__ agg,
                                                   float* __restrict__ stats, int N,
                                                   float invSlice) {
    __shared__ float part[WPB][NPW][HDIM];   // 6656 B
    __shared__ float lss[WPB][8][4], lsq[WPB][8][4];
    const int tid = threadIdx.x;
    const int lane = tid & 63;
    const int w = tid >> 6;
    const int j8 = lane & 7;    // uint2 index within row -> features [4*j8, 4*j8+4)
    const int oct = lane >> 3;  // 0..7, oct o owns edges e ≡ o (mod 8)
    const int wid = blockIdx.x * WPB + w;
    const int n0 = wid * NPW;   // contiguous node chunk per wave
    const float4 b4 = *(const float4*)&bias[4 * j8];

    // zero this wave's partials (wave-private, no barrier needed)
    for (int i = lane; i < NPW * HDIM; i += 64) ((float*)part[w])[i] = 0.f;

    for (int s = 0; s < NSLICE; ++s) {
        __syncthreads();  // loose intra-block phase alignment
        for (int i = 0; i < NPW; ++i) {
            const int n = n0 + i;
            if (n >= N) break;
            const int beg = noffS[(size_t)n * NSLICE + s];
            const int end = noffS[(size_t)n * NSLICE + s + 1];
            float a0 = 0, a1 = 0, a2 = 0, a3 = 0;
            if (oct == 0) {  // self-loop in its own slice's phase (keeps the read L2-local)
                int ss = (int)((float)n * invSlice); if (ss > NSLICE - 1) ss = NSLICE - 1;
                if (ss == s) {
                    uint2 u = hp8[(size_t)n * 8 + j8];
                    a0 = blo(u.x); a1 = bhi(u.x); a2 = blo(u.y); a3 = bhi(u.y);
                }
            }
            int e = beg + oct;
            // rung A: 4 loads in flight, 32 edges/wave-iter
            for (; e + 24 < end; e += 32) {
                int rr[4]; uint2 uu[4];
#pragma unroll
                for (int k = 0; k < 4; ++k) rr[k] = __builtin_nontemporal_load(&srcs[e + 8 * k]);
#pragma unroll
                for (int k = 0; k < 4; ++k) uu[k] = hp8[(size_t)rr[k] * 8 + j8];
#pragma unroll
                for (int k = 0; k < 4; ++k) {
                    a0 += blo(uu[k].x); a1 += bhi(uu[k].x);
                    a2 += blo(uu[k].y); a3 += bhi(uu[k].y);
                }
            }
            // rung B: 2 loads, 16 edges
            if (e + 8 < end) {
                int r0 = __builtin_nontemporal_load(&srcs[e]);
                int r1 = __builtin_nontemporal_load(&srcs[e + 8]);
                uint2 u0 = hp8[(size_t)r0 * 8 + j8];
                uint2 u1 = hp8[(size_t)r1 * 8 + j8];
                a0 += blo(u0.x) + blo(u1.x); a1 += bhi(u0.x) + bhi(u1.x);
                a2 += blo(u0.y) + blo(u1.y); a3 += bhi(u0.y) + bhi(u1.y);
                e += 16;
            }
            // rung C: singles
            for (; e < end; e += 8) {
                int r0 = __builtin_nontemporal_load(&srcs[e]);
                uint2 u = hp8[(size_t)r0 * 8 + j8];
                a0 += blo(u.x); a1 += bhi(u.x); a2 += blo(u.y); a3 += bhi(u.y);
            }
            // combine octs (xor 8/16/32 preserves j8)
#pragma unroll
            for (int off = 8; off < 64; off <<= 1) {
                a0 += __shfl_xor(a0, off);
                a1 += __shfl_xor(a1, off);
                a2 += __shfl_xor(a2, off);
                a3 += __shfl_xor(a3, off);
            }
            if (oct == 0) {
                float4 p = *(float4*)&part[w][i][4 * j8];
                p.x += a0; p.y += a1; p.z += a2; p.w += a3;
                *(float4*)&part[w][i][4 * j8] = p;
            }
        }
    }

    // epilogue: bias, write agg, accumulate BN stats
    float s0 = 0, s1 = 0, s2 = 0, s3 = 0;
    float q0 = 0, q1 = 0, q2 = 0, q3 = 0;
    for (int i = 0; i < NPW; ++i) {
        const int n = n0 + i;
        if (n >= N) break;
        if (oct == 0) {
            float4 p = *(float4*)&part[w][i][4 * j8];
            float d = dinv[n];
            float o0 = fmaf(d, p.x, b4.x), o1 = fmaf(d, p.y, b4.y);
            float o2 = fmaf(d, p.z, b4.z), o3 = fmaf(d, p.w, b4.w);
            *(float4*)&agg[(size_t)n * HDIM + 4 * j8] = make_float4(o0, o1, o2, o3);
            s0 += o0; s1 += o1; s2 += o2; s3 += o3;
            q0 += o0 * o0; q1 += o1 * o1; q2 += o2 * o2; q3 += o3 * o3;
        }
    }
    if (oct == 0) {
        lss[w][j8][0] = s0; lss[w][j8][1] = s1; lss[w][j8][2] = s2; lss[w][j8][3] = s3;
        lsq[w][j8][0] = q0; lsq[w][j8][1] = q1; lsq[w][j8][2] = q2; lsq[w][j8][3] = q3;
    }
    __syncthreads();
    if (tid < 32) {
        int jj = tid >> 2, k = tid & 3;  // feature = tid = 4*jj + k
        float A = 0, Bq = 0;
#pragma unroll
        for (int ww = 0; ww < WPB; ++ww) { A += lss[ww][jj][k]; Bq += lsq[ww][jj][k]; }
        atomicAdd(&stats[tid], A);
        atomicAdd(&stats[HDIM + tid], Bq);
    }
}

// ---------- final batchnorm apply (layer 2, no relu), float4 ----------
__global__ void k_bnapply(const float* __restrict__ a, const float* __restrict__ stats,
                          const float* __restrict__ gamma, const float* __restrict__ beta,
                          float* __restrict__ out, int n, float invN) {
    int i = (blockIdx.x * 256 + threadIdx.x) * 4;
    if (i < n * HDIM) {
        int j = i & 31;
        float4 v = *(const float4*)&a[i];
        float r[4];
        float* vp = &v.x;
#pragma unroll
        for (int k = 0; k < 4; ++k) {
            float mean = stats[j + k] * invN;
            float var = stats[HDIM + j + k] * invN - mean * mean;
            float g = gamma[j + k] * rsqrtf(var + BN_EPS);
            r[k] = (vp[k] - mean) * g + beta[j + k];
        }
        *(float4*)&out[i] = make_float4(r[0], r[1], r[2], r[3]);
    }
}

extern "C" void kernel_launch(void* const* d_in, const int* in_sizes, int n_in,
                              void* d_out, int out_size, void* d_ws, size_t ws_size,
                              hipStream_t stream) {
    const float* x   = (const float*)d_in[0];
    const int*   ei  = (const int*)d_in[1];
    const float* W1  = (const float*)d_in[2];
    const float* b1  = (const float*)d_in[3];
    const float* g1  = (const float*)d_in[4];
    const float* be1 = (const float*)d_in[5];
    const float* W2  = (const float*)d_in[6];
    const float* b2  = (const float*)d_in[7];
    const float* g2  = (const float*)d_in[8];
    const float* be2 = (const float*)d_in[9];

    const int N = in_sizes[0] / FDIM;
    const int E = in_sizes[1] / 2;
    const int* row = ei;      // source
    const int* col = ei + E;  // target
    const int B = (N + BK - 1) / BK;   // buckets (391 for N=100k, fits BMAX)

    char* p = (char*)d_ws;
    auto alloc = [&](size_t bytes) { char* r = p; p += (bytes + 255) & ~(size_t)255; return r; };
    float*          dinv    = (float*)alloc((size_t)N * 4);
    int*            bcounts = (int*)alloc((size_t)B * 4);
    int*            boff    = (int*)alloc((size_t)(B + 1) * 4);
    int*            bcur    = (int*)alloc((size_t)B * 4);
    int*            noffS   = (int*)alloc(((size_t)N * NSLICE + 1) * 4);
    unsigned*       pairs   = (unsigned*)alloc((size_t)E * 4);
    int*            srcs    = (int*)alloc((size_t)E * 4);
    __hip_bfloat16* B1      = (__hip_bfloat16*)alloc((size_t)N * HDIM * 2);  // hp [N][32] bf16
    float*          B2      = (float*)alloc((size_t)N * HDIM * 4);           // agg (fp32)
    float*          stats   = (float*)alloc(512);  // layer1 [0,64), layer2 [64,128)

    const float invN = 1.0f / (float)N;
    const int sliceSz = (N + NSLICE - 1) / NSLICE;
    const float invSlice = 1.0f / (float)sliceSz;
    const int EBH = (E + CHUNK_H - 1) / CHUNK_H;
    const int EBP = (E + CHUNK_P - 1) / CHUNK_P;
    const int AGG_BLOCKS = (N + WPB * NPW - 1) / (WPB * NPW);  // 1924 for N=100k: all resident

    (void)hipMemsetAsync(bcounts, 0, (size_t)B * 4, stream);
    (void)hipMemsetAsync(stats, 0, 512, stream);

    // bucketed edge partition + per-bucket (dst, src-slice) counting sort -> CSR segments
    k_hist2<<<EBH, 256, 0, stream>>>(col, bcounts, E, B);
    k_bscan<<<1, 256, 0, stream>>>(bcounts, boff, bcur, noffS, B, E, N);
    k_partition<<<EBP, 256, 0, stream>>>(row, col, bcur, pairs, E, B);
    k_sort<<<B, 1024, 0, stream>>>(pairs, boff, srcs, noffS, dinv, N, invSlice);

    // layer 1
    k_gemm<FDIM, false><<<(N + 7) / 8, 256, 0, stream>>>(x, W1, dinv, B1, N,
                                                         nullptr, nullptr, nullptr, 0.f);
    k_aggregate<<<AGG_BLOCKS, 256, 0, stream>>>((const uint2*)B1, dinv, noffS, srcs, b1,
                                                B2, stats, N, invSlice);

    // layer 2 (BN1+ReLU fused into gemm2's X load)
    k_gemm<HDIM, true><<<(N + 7) / 8, 256, 0, stream>>>(B2, W2, dinv, B1, N,
                                                        stats, g1, be1, invN);
    k_aggregate<<<AGG_BLOCKS, 256, 0, stream>>>((const uint2*)B1, dinv, noffS, srcs, b2,
                                                B2, stats + 2 * HDIM, N, invSlice);
    k_bnapply<<<(N * HDIM / 4 + 255) / 256, 256, 0, stream>>>(B2, stats + 2 * HDIM, g2, be2,
                                                              (float*)d_out, N, invN);
}

// Round 2
// 577.145 us; speedup vs baseline: 1.2126x; 1.2126x over previous
//
#include <hip/hip_runtime.h>
#include <hip/hip_bf16.h>

#define FDIM 128
#define HDIM 32
#define BN_EPS 1e-5f
#define BK 256         // destination nodes per bucket
#define NBITS 8        // log2(BK)
#define CHUNK_H 4096   // edges per hist block
#define CHUNK_P 4096   // edges per partition block
#define BMAX 512       // max buckets (N <= 131072)
#define NSLICE 4       // src slices: ~1.6MB bf16 table slice -> fits per-XCD 4MB L2
#define SBINS (BK * NSLICE)
#define NPO 2          // nodes per oct in aggregate
#define NPW (8 * NPO)  // 16 nodes per wave
#define WPB 4          // waves per block -> 64 nodes per block

// ---------- per-bucket histogram (LDS) ----------
__global__ void k_hist2(const int* __restrict__ col, int* __restrict__ bcounts, int E, int B) {
    __shared__ int h[BMAX];
    for (int i = threadIdx.x; i < B; i += 256) h[i] = 0;
    __syncthreads();
    int base = blockIdx.x * CHUNK_H;
    int end = min(base + CHUNK_H, E);
    for (int e = base + threadIdx.x; e < end; e += 256)
        atomicAdd(&h[col[e] >> NBITS], 1);
    __syncthreads();
    for (int i = threadIdx.x; i < B; i += 256)
        if (h[i]) atomicAdd(&bcounts[i], h[i]);
}

// ---------- single-block exclusive scan of bucket counts ----------
__global__ void k_bscan(const int* __restrict__ bcounts, int* __restrict__ boff,
                        int* __restrict__ bcur, int* __restrict__ noffS, int B, int E, int N) {
    __shared__ int tsum[256];
    __shared__ int wtot[4];
    const int t = threadIdx.x;
    const int per = (B + 255) / 256;
    const int b0 = t * per;
    int s = 0;
    for (int k = 0; k < per; ++k) { int i = b0 + k; if (i < B) s += bcounts[i]; }
    tsum[t] = s;
    __syncthreads();
    int lane = t & 63, w = t >> 6;
    int v = tsum[t];
    int inc = v;
    for (int off = 1; off < 64; off <<= 1) {
        int u = __shfl_up(inc, off);
        if (lane >= off) inc += u;
    }
    if (lane == 63) wtot[w] = inc;
    __syncthreads();
    int pre = 0;
    for (int k = 0; k < w; ++k) pre += wtot[k];
    int acc = pre + inc - v;  // exclusive prefix
    for (int k = 0; k < per; ++k) {
        int i = b0 + k;
        if (i < B) { boff[i] = acc; bcur[i] = acc; acc += bcounts[i]; }
    }
    if (t == 0) { boff[B] = E; noffS[(size_t)N * NSLICE] = E; }
}

// ---------- partition with LDS staging: pairs[] grouped by dst bucket, coalesced writes ----------
__global__ __launch_bounds__(256) void k_partition(const int* __restrict__ row,
                                                   const int* __restrict__ col,
                                                   int* __restrict__ bcur,
                                                   unsigned* __restrict__ pairs,
                                                   int E, int B) {
    __shared__ int h[BMAX];          // counts -> local cursors
    __shared__ int lbase[BMAX + 1];  // local exclusive scan
    __shared__ int delta[BMAX];      // global_base - local_base
    __shared__ unsigned pk[CHUNK_P]; // bucket-sorted packed pairs
    const int t = threadIdx.x;
    const int base = blockIdx.x * CHUNK_P;
    const int end = min(base + CHUNK_P, E);

    for (int i = t; i < B; i += 256) h[i] = 0;
    __syncthreads();
    for (int e = base + t; e < end; e += 256)
        atomicAdd(&h[col[e] >> NBITS], 1);
    __syncthreads();
    if (t < 64) {
        int carry = 0;
        for (int bb = 0; bb < B; bb += 64) {
            int idx = bb + t;
            int v = (idx < B) ? h[idx] : 0;
            int inc = v;
            for (int off = 1; off < 64; off <<= 1) {
                int u = __shfl_up(inc, off);
                if (t >= off) inc += u;
            }
            if (idx < B) lbase[idx] = carry + inc - v;
            carry += __shfl(inc, 63);
        }
        if (t == 0) lbase[B] = carry;
    }
    __syncthreads();
    for (int b = t; b < B; b += 256) {
        int c = h[b];
        if (c) {
            int g = atomicAdd(&bcur[b], c);
            delta[b] = g - lbase[b];
        }
    }
    __syncthreads();
    for (int b = t; b < B; b += 256) h[b] = lbase[b];
    __syncthreads();
    for (int e = base + t; e < end; e += 256) {
        int c = col[e], r = row[e];
        int lpos = atomicAdd(&h[c >> NBITS], 1);
        pk[lpos] = ((unsigned)r << NBITS) | (unsigned)(c & (BK - 1));
    }
    __syncthreads();
    const int tot = lbase[B];
    for (int i = t; i < tot; i += 256) {
        int lo = 0, hi = B - 1;
        while (lo < hi) {
            int mid = (lo + hi + 1) >> 1;
            if (lbase[mid] <= i) lo = mid; else hi = mid - 1;
        }
        pairs[delta[lo] + i] = pk[i];
    }
}

// ---------- per-bucket counting sort by (dst, src-slice) -> CSR segments noffS + dinv ----------
__global__ __launch_bounds__(1024) void k_sort(const unsigned* __restrict__ pairs,
                                               const int* __restrict__ boff,
                                               int* __restrict__ srcs, int* __restrict__ noffS,
                                               float* __restrict__ dinv, int N, float invSlice) {
    __shared__ int cnt[SBINS];
    __shared__ int cur[SBINS];
    const int bb = blockIdx.x;
    const int t = threadIdx.x;
    cnt[t] = 0;   // blockDim == SBINS == 1024
    __syncthreads();
    const int beg = boff[bb], end = boff[bb + 1];
    for (int i = beg + t; i < end; i += 1024) {
        unsigned p = pairs[i];
        int src = (int)(p >> NBITS);
        int s = (int)((float)src * invSlice); if (s > NSLICE - 1) s = NSLICE - 1;
        atomicAdd(&cnt[(((int)p & (BK - 1)) << 2) | s], 1);
    }
    __syncthreads();
    if (t < 64) {
        int carry = 0;
        for (int base = 0; base < SBINS; base += 64) {
            int v = cnt[base + t];
            int inc = v;
            for (int off = 1; off < 64; off <<= 1) {
                int u = __shfl_up(inc, off);
                if (t >= off) inc += u;
            }
            cur[base + t] = beg + carry + inc - v;
            carry += __shfl(inc, 63);
        }
    }
    __syncthreads();
    {   // bin t == local_node*(NSLICE) + slice; write segment start
        int n = bb * BK + (t >> 2);
        if (n < N) noffS[(size_t)n * NSLICE + (t & 3)] = cur[t];
    }
    if (t < BK) {
        int n = bb * BK + t;
        if (n < N) {
            int tot = cnt[(t << 2)] + cnt[(t << 2) | 1] + cnt[(t << 2) | 2] + cnt[(t << 2) | 3];
            dinv[n] = rsqrtf((float)(tot + 1));  // +1 self-loop
        }
    }
    __syncthreads();
    for (int i = beg + t; i < end; i += 1024) {
        unsigned p = pairs[i];
        int src = (int)(p >> NBITS);
        int s = (int)((float)src * invSlice); if (s > NSLICE - 1) s = NSLICE - 1;
        int pos = atomicAdd(&cur[(((int)p & (BK - 1)) << 2) | s], 1);
        srcs[pos] = src;
    }
}

// ---------- GEMM: Y[n,32] = bf16(dinv[n]*(X[n,K]@W[K,32])); optional fused BN+ReLU on X ----------
template <int K, bool APPLY_BN>
__global__ void k_gemm(const float* __restrict__ X, const float* __restrict__ W,
                       const float* __restrict__ dinv, __hip_bfloat16* __restrict__ Y, int n,
                       const float* __restrict__ stats, const float* __restrict__ gamma,
                       const float* __restrict__ beta, float invN) {
    __shared__ __align__(16) float Ws[K * HDIM];
    __shared__ __align__(16) float Xs[8 * K];
    __shared__ float bnsc[K], bnsh[K];
    const int tid = threadIdx.x;
    const int row0 = blockIdx.x * 8;

    if (APPLY_BN) {
        if (tid < K) {
            float mean = stats[tid] * invN;
            float var = stats[K + tid] * invN - mean * mean;
            float sc = gamma[tid] * rsqrtf(var + BN_EPS);
            bnsc[tid] = sc;
            bnsh[tid] = beta[tid] - mean * sc;
        }
        __syncthreads();
    }
    for (int i = tid * 4; i < K * HDIM; i += 1024) {
        *(float4*)&Ws[i] = *(const float4*)&W[i];
    }
    for (int i = tid * 4; i < 8 * K; i += 1024) {
        int r = i / K, k = i % K;
        int gr = row0 + r;
        float4 v = make_float4(0.f, 0.f, 0.f, 0.f);
        if (gr < n) v = *(const float4*)&X[(size_t)gr * K + k];
        if (APPLY_BN) {
            v.x = fmaxf(v.x * bnsc[k]     + bnsh[k],     0.f);
            v.y = fmaxf(v.y * bnsc[k + 1] + bnsh[k + 1], 0.f);
            v.z = fmaxf(v.z * bnsc[k + 2] + bnsh[k + 2], 0.f);
            v.w = fmaxf(v.w * bnsc[k + 3] + bnsh[k + 3], 0.f);
        }
        *(float4*)&Xs[i] = v;
    }
    __syncthreads();
    const int r = tid >> 5, c = tid & 31;
    const int grow = row0 + r;
    if (grow < n) {
        float acc = 0.f;
#pragma unroll
        for (int k = 0; k < K; ++k) acc += Xs[r * K + k] * Ws[k * HDIM + c];
        Y[(size_t)grow * HDIM + c] = __float2bfloat16(dinv[grow] * acc);
    }
}

// bf16 pair unpack via bit ops (no cvt)
__device__ __forceinline__ float blo(unsigned u) { return __uint_as_float(u << 16); }
__device__ __forceinline__ float bhi(unsigned u) { return __uint_as_float(u & 0xffff0000u); }

// ---------- slice-phased gather-aggregate, oct-per-node ----------
// Edges sorted by (dst, src-slice). Each oct (8 lanes) owns NPO whole nodes: the 8 lanes
// jointly fetch full 64B rows (lane j8 -> features [4*j8,4*j8+4)), accumulators live in
// registers across slices -> ZERO cross-lane reductions, no LDS partials.
// All resident blocks sweep slices in phase so per-XCD L2 holds the active ~1.6MB slice.
#define AGG_SEG(A, BEG, END, SELF, NNODE)                                        \
    {                                                                            \
        float a0 = 0, a1 = 0, a2 = 0, a3 = 0;                                    \
        if (SELF) {                                                              \
            uint2 u = hp8[(size_t)(NNODE) * 8 + j8];                             \
            a0 = blo(u.x); a1 = bhi(u.x); a2 = blo(u.y); a3 = bhi(u.y);          \
        }                                                                        \
        int e = (BEG), endv = (END);                                             \
        for (; e + 7 < endv; e += 8) {                                           \
            int r0 = srcs[e],     r1 = srcs[e + 1], r2 = srcs[e + 2];            \
            int r3 = srcs[e + 3], r4 = srcs[e + 4], r5 = srcs[e + 5];            \
            int r6 = srcs[e + 6], r7 = srcs[e + 7];                              \
            uint2 u0 = hp8[(size_t)r0 * 8 + j8], u1 = hp8[(size_t)r1 * 8 + j8];  \
            uint2 u2 = hp8[(size_t)r2 * 8 + j8], u3 = hp8[(size_t)r3 * 8 + j8];  \
            uint2 u4 = hp8[(size_t)r4 * 8 + j8], u5 = hp8[(size_t)r5 * 8 + j8];  \
            uint2 u6 = hp8[(size_t)r6 * 8 + j8], u7 = hp8[(size_t)r7 * 8 + j8];  \
            a0 += blo(u0.x) + blo(u1.x) + blo(u2.x) + blo(u3.x)                  \
                + blo(u4.x) + blo(u5.x) + blo(u6.x) + blo(u7.x);                 \
            a1 += bhi(u0.x) + bhi(u1.x) + bhi(u2.x) + bhi(u3.x)                  \
                + bhi(u4.x) + bhi(u5.x) + bhi(u6.x) + bhi(u7.x);                 \
            a2 += blo(u0.y) + blo(u1.y) + blo(u2.y) + blo(u3.y)                  \
                + blo(u4.y) + blo(u5.y) + blo(u6.y) + blo(u7.y);                 \
            a3 += bhi(u0.y) + bhi(u1.y) + bhi(u2.y) + bhi(u3.y)                  \
                + bhi(u4.y) + bhi(u5.y) + bhi(u6.y) + bhi(u7.y);                 \
        }                                                                        \
        if (e + 3 < endv) {                                                      \
            int r0 = srcs[e], r1 = srcs[e + 1], r2 = srcs[e + 2],                \
                r3 = srcs[e + 3];                                                \
            uint2 u0 = hp8[(size_t)r0 * 8 + j8], u1 = hp8[(size_t)r1 * 8 + j8];  \
            uint2 u2 = hp8[(size_t)r2 * 8 + j8], u3 = hp8[(size_t)r3 * 8 + j8];  \
            a0 += blo(u0.x) + blo(u1.x) + blo(u2.x) + blo(u3.x);                 \
            a1 += bhi(u0.x) + bhi(u1.x) + bhi(u2.x) + bhi(u3.x);                 \
            a2 += blo(u0.y) + blo(u1.y) + blo(u2.y) + blo(u3.y);                 \
            a3 += bhi(u0.y) + bhi(u1.y) + bhi(u2.y) + bhi(u3.y);                 \
            e += 4;                                                              \
        }                                                                        \
        for (; e < endv; ++e) {                                                  \
            uint2 u = hp8[(size_t)srcs[e] * 8 + j8];                             \
            a0 += blo(u.x); a1 += bhi(u.x); a2 += blo(u.y); a3 += bhi(u.y);      \
        }                                                                        \
        A##0 += a0; A##1 += a1; A##2 += a2; A##3 += a3;                          \
    }

__global__ __launch_bounds__(256) void k_aggregate(const uint2* __restrict__ hp8,
                                                   const float* __restrict__ dinv,
                                                   const int* __restrict__ noffS,
                                                   const int* __restrict__ srcs,
                                                   const float* __restrict__ bias,
                                                   float* __restrict__ agg,
                                                   float* __restrict__ stats, int N,
                                                   float invSlice) {
    __shared__ float lss[WPB][64][4], lsq[WPB][64][4];
    const int tid = threadIdx.x;
    const int lane = tid & 63;
    const int w = tid >> 6;
    const int j8 = lane & 7;    // uint2 index within row -> features [4*j8, 4*j8+4)
    const int oct = lane >> 3;  // this oct owns nodes nb, nb+1
    const int nb = (blockIdx.x * WPB + w) * NPW + oct * NPO;
    const float4 b4 = *(const float4*)&bias[4 * j8];

    // hoist all segment boundaries: noffS[n*4 .. n*4+4] (int4 + scalar, 16B-aligned)
    int o00, o01, o02, o03, o04, ss0;
    int o10, o11, o12, o13, o14, ss1;
    if (nb < N) {
        int4 o = *(const int4*)&noffS[(size_t)nb * NSLICE];
        o00 = o.x; o01 = o.y; o02 = o.z; o03 = o.w;
        o04 = noffS[(size_t)nb * NSLICE + 4];
        ss0 = (int)((float)nb * invSlice); if (ss0 > NSLICE - 1) ss0 = NSLICE - 1;
    } else { o00 = o01 = o02 = o03 = o04 = 0; ss0 = -1; }
    if (nb + 1 < N) {
        int4 o = *(const int4*)&noffS[(size_t)(nb + 1) * NSLICE];
        o10 = o.x; o11 = o.y; o12 = o.z; o13 = o.w;
        o14 = noffS[(size_t)(nb + 1) * NSLICE + 4];
        ss1 = (int)((float)(nb + 1) * invSlice); if (ss1 > NSLICE - 1) ss1 = NSLICE - 1;
    } else { o10 = o11 = o12 = o13 = o14 = 0; ss1 = -1; }

    float A0 = 0, A1 = 0, A2 = 0, A3 = 0;   // node nb accum (features 4*j8..)
    float C0 = 0, C1 = 0, C2 = 0, C3 = 0;   // node nb+1 accum

    // slice phases (unrolled; all offsets compile-time-indexed -> registers)
    __syncthreads();
    AGG_SEG(A, o00, o01, ss0 == 0, nb);
    AGG_SEG(C, o10, o11, ss1 == 0, nb + 1);
    __syncthreads();
    AGG_SEG(A, o01, o02, ss0 == 1, nb);
    AGG_SEG(C, o11, o12, ss1 == 1, nb + 1);
    __syncthreads();
    AGG_SEG(A, o02, o03, ss0 == 2, nb);
    AGG_SEG(C, o12, o13, ss1 == 2, nb + 1);
    __syncthreads();
    AGG_SEG(A, o03, o04, ss0 == 3, nb);
    AGG_SEG(C, o13, o14, ss1 == 3, nb + 1);

    // epilogue: bias, write agg rows (8 lanes x 16B = 128B contiguous per node), BN stats
    float s0 = 0, s1 = 0, s2 = 0, s3 = 0;
    float q0 = 0, q1 = 0, q2 = 0, q3 = 0;
    if (nb < N) {
        float d = dinv[nb];
        float p0 = fmaf(d, A0, b4.x), p1 = fmaf(d, A1, b4.y);
        float p2 = fmaf(d, A2, b4.z), p3 = fmaf(d, A3, b4.w);
        *(float4*)&agg[(size_t)nb * HDIM + 4 * j8] = make_float4(p0, p1, p2, p3);
        s0 += p0; s1 += p1; s2 += p2; s3 += p3;
        q0 += p0 * p0; q1 += p1 * p1; q2 += p2 * p2; q3 += p3 * p3;
    }
    if (nb + 1 < N) {
        float d = dinv[nb + 1];
        float p0 = fmaf(d, C0, b4.x), p1 = fmaf(d, C1, b4.y);
        float p2 = fmaf(d, C2, b4.z), p3 = fmaf(d, C3, b4.w);
        *(float4*)&agg[(size_t)(nb + 1) * HDIM + 4 * j8] = make_float4(p0, p1, p2, p3);
        s0 += p0; s1 += p1; s2 += p2; s3 += p3;
        q0 += p0 * p0; q1 += p1 * p1; q2 += p2 * p2; q3 += p3 * p3;
    }
    lss[w][lane][0] = s0; lss[w][lane][1] = s1; lss[w][lane][2] = s2; lss[w][lane][3] = s3;
    lsq[w][lane][0] = q0; lsq[w][lane][1] = q1; lsq[w][lane][2] = q2; lsq[w][lane][3] = q3;
    __syncthreads();
    if (tid < 32) {
        int jj = tid >> 2, k = tid & 3;  // feature = tid = 4*jj + k
        float A = 0, Bq = 0;
#pragma unroll
        for (int ww = 0; ww < WPB; ++ww)
            for (int o = 0; o < 8; ++o) {
                A  += lss[ww][o * 8 + jj][k];
                Bq += lsq[ww][o * 8 + jj][k];
            }
        atomicAdd(&stats[tid], A);
        atomicAdd(&stats[HDIM + tid], Bq);
    }
}

// ---------- final batchnorm apply (layer 2, no relu), float4 ----------
__global__ void k_bnapply(const float* __restrict__ a, const float* __restrict__ stats,
                          const float* __restrict__ gamma, const float* __restrict__ beta,
                          float* __restrict__ out, int n, float invN) {
    int i = (blockIdx.x * 256 + threadIdx.x) * 4;
    if (i < n * HDIM) {
        int j = i & 31;
        float4 v = *(const float4*)&a[i];
        float r[4];
        float* vp = &v.x;
#pragma unroll
        for (int k = 0; k < 4; ++k) {
            float mean = stats[j + k] * invN;
            float var = stats[HDIM + j + k] * invN - mean * mean;
            float g = gamma[j + k] * rsqrtf(var + BN_EPS);
            r[k] = (vp[k] - mean) * g + beta[j + k];
        }
        *(float4*)&out[i] = make_float4(r[0], r[1], r[2], r[3]);
    }
}

extern "C" void kernel_launch(void* const* d_in, const int* in_sizes, int n_in,
                              void* d_out, int out_size, void* d_ws, size_t ws_size,
                              hipStream_t stream) {
    const float* x   = (const float*)d_in[0];
    const int*   ei  = (const int*)d_in[1];
    const float* W1  = (const float*)d_in[2];
    const float* b1  = (const float*)d_in[3];
    const float* g1  = (const float*)d_in[4];
    const float* be1 = (const float*)d_in[5];
    const float* W2  = (const float*)d_in[6];
    const float* b2  = (const float*)d_in[7];
    const float* g2  = (const float*)d_in[8];
    const float* be2 = (const float*)d_in[9];

    const int N = in_sizes[0] / FDIM;
    const int E = in_sizes[1] / 2;
    const int* row = ei;      // source
    const int* col = ei + E;  // target
    const int B = (N + BK - 1) / BK;   // buckets (391 for N=100k, fits BMAX)

    char* p = (char*)d_ws;
    auto alloc = [&](size_t bytes) { char* r = p; p += (bytes + 255) & ~(size_t)255; return r; };
    float*          dinv    = (float*)alloc((size_t)N * 4);
    int*            bcounts = (int*)alloc((size_t)B * 4);
    int*            boff    = (int*)alloc((size_t)(B + 1) * 4);
    int*            bcur    = (int*)alloc((size_t)B * 4);
    int*            noffS   = (int*)alloc(((size_t)N * NSLICE + 1) * 4);
    unsigned*       pairs   = (unsigned*)alloc((size_t)E * 4);
    int*            srcs    = (int*)alloc((size_t)E * 4);
    __hip_bfloat16* B1      = (__hip_bfloat16*)alloc((size_t)N * HDIM * 2);  // hp [N][32] bf16
    float*          B2      = (float*)alloc((size_t)N * HDIM * 4);           // agg (fp32)
    float*          stats   = (float*)alloc(512);  // layer1 [0,64), layer2 [64,128)

    const float invN = 1.0f / (float)N;
    const int sliceSz = (N + NSLICE - 1) / NSLICE;
    const float invSlice = 1.0f / (float)sliceSz;
    const int EBH = (E + CHUNK_H - 1) / CHUNK_H;
    const int EBP = (E + CHUNK_P - 1) / CHUNK_P;
    const int AGG_BLOCKS = (N + WPB * NPW - 1) / (WPB * NPW);  // 1563 for N=100k: all resident

    (void)hipMemsetAsync(bcounts, 0, (size_t)B * 4, stream);
    (void)hipMemsetAsync(stats, 0, 512, stream);

    // bucketed edge partition + per-bucket (dst, src-slice) counting sort -> CSR segments
    k_hist2<<<EBH, 256, 0, stream>>>(col, bcounts, E, B);
    k_bscan<<<1, 256, 0, stream>>>(bcounts, boff, bcur, noffS, B, E, N);
    k_partition<<<EBP, 256, 0, stream>>>(row, col, bcur, pairs, E, B);
    k_sort<<<B, 1024, 0, stream>>>(pairs, boff, srcs, noffS, dinv, N, invSlice);

    // layer 1
    k_gemm<FDIM, false><<<(N + 7) / 8, 256, 0, stream>>>(x, W1, dinv, B1, N,
                                                         nullptr, nullptr, nullptr, 0.f);
    k_aggregate<<<AGG_BLOCKS, 256, 0, stream>>>((const uint2*)B1, dinv, noffS, srcs, b1,
                                                B2, stats, N, invSlice);

    // layer 2 (BN1+ReLU fused into gemm2's X load)
    k_gemm<HDIM, true><<<(N + 7) / 8, 256, 0, stream>>>(B2, W2, dinv, B1, N,
                                                        stats, g1, be1, invN);
    k_aggregate<<<AGG_BLOCKS, 256, 0, stream>>>((const uint2*)B1, dinv, noffS, srcs, b2,
                                                B2, stats + 2 * HDIM, N, invSlice);
    k_bnapply<<<(N * HDIM / 4 + 255) / 256, 256, 0, stream>>>(B2, stats + 2 * HDIM, g2, be2,
                                                              (float*)d_out, N, invN);
}

// Round 3
// 523.961 us; speedup vs baseline: 1.3357x; 1.1015x over previous
//
#include <hip/hip_runtime.h>
#include <hip/hip_bf16.h>

#define FDIM 128
#define HDIM 32
#define BN_EPS 1e-5f
#define BK 256         // destination nodes per bucket
#define NBITS 8        // log2(BK)
#define CHUNK_H 4096   // edges per hist block
#define CHUNK_P 4096   // edges per partition block
#define BMAX 512       // max buckets (N <= 131072)
#define NSLICE 4       // src slices: ~1.6MB bf16 table slice -> fits per-XCD 4MB L2
#define SBINS (BK * NSLICE)
#define WPB 4          // waves per block; 16 quads/wave, 1 node/quad -> 64 nodes/block

// ---------- per-bucket histogram (LDS) ----------
__global__ void k_hist2(const int* __restrict__ col, int* __restrict__ bcounts, int E, int B) {
    __shared__ int h[BMAX];
    for (int i = threadIdx.x; i < B; i += 256) h[i] = 0;
    __syncthreads();
    int base = blockIdx.x * CHUNK_H;
    int end = min(base + CHUNK_H, E);
    for (int e = base + threadIdx.x; e < end; e += 256)
        atomicAdd(&h[col[e] >> NBITS], 1);
    __syncthreads();
    for (int i = threadIdx.x; i < B; i += 256)
        if (h[i]) atomicAdd(&bcounts[i], h[i]);
}

// ---------- single-block exclusive scan of bucket counts ----------
__global__ void k_bscan(const int* __restrict__ bcounts, int* __restrict__ boff,
                        int* __restrict__ bcur, int* __restrict__ noffS, int B, int E, int N) {
    __shared__ int tsum[256];
    __shared__ int wtot[4];
    const int t = threadIdx.x;
    const int per = (B + 255) / 256;
    const int b0 = t * per;
    int s = 0;
    for (int k = 0; k < per; ++k) { int i = b0 + k; if (i < B) s += bcounts[i]; }
    tsum[t] = s;
    __syncthreads();
    int lane = t & 63, w = t >> 6;
    int v = tsum[t];
    int inc = v;
    for (int off = 1; off < 64; off <<= 1) {
        int u = __shfl_up(inc, off);
        if (lane >= off) inc += u;
    }
    if (lane == 63) wtot[w] = inc;
    __syncthreads();
    int pre = 0;
    for (int k = 0; k < w; ++k) pre += wtot[k];
    int acc = pre + inc - v;  // exclusive prefix
    for (int k = 0; k < per; ++k) {
        int i = b0 + k;
        if (i < B) { boff[i] = acc; bcur[i] = acc; acc += bcounts[i]; }
    }
    if (t == 0) { boff[B] = E; noffS[(size_t)N * NSLICE] = E; }
}

// ---------- partition with LDS staging: pairs[] grouped by dst bucket, coalesced writes ----------
__global__ __launch_bounds__(256) void k_partition(const int* __restrict__ row,
                                                   const int* __restrict__ col,
                                                   int* __restrict__ bcur,
                                                   unsigned* __restrict__ pairs,
                                                   int E, int B) {
    __shared__ int h[BMAX];          // counts -> local cursors
    __shared__ int lbase[BMAX + 1];  // local exclusive scan
    __shared__ int delta[BMAX];      // global_base - local_base
    __shared__ unsigned pk[CHUNK_P]; // bucket-sorted packed pairs
    const int t = threadIdx.x;
    const int base = blockIdx.x * CHUNK_P;
    const int end = min(base + CHUNK_P, E);

    for (int i = t; i < B; i += 256) h[i] = 0;
    __syncthreads();
    for (int e = base + t; e < end; e += 256)
        atomicAdd(&h[col[e] >> NBITS], 1);
    __syncthreads();
    if (t < 64) {
        int carry = 0;
        for (int bb = 0; bb < B; bb += 64) {
            int idx = bb + t;
            int v = (idx < B) ? h[idx] : 0;
            int inc = v;
            for (int off = 1; off < 64; off <<= 1) {
                int u = __shfl_up(inc, off);
                if (t >= off) inc += u;
            }
            if (idx < B) lbase[idx] = carry + inc - v;
            carry += __shfl(inc, 63);
        }
        if (t == 0) lbase[B] = carry;
    }
    __syncthreads();
    for (int b = t; b < B; b += 256) {
        int c = h[b];
        if (c) {
            int g = atomicAdd(&bcur[b], c);
            delta[b] = g - lbase[b];
        }
    }
    __syncthreads();
    for (int b = t; b < B; b += 256) h[b] = lbase[b];
    __syncthreads();
    for (int e = base + t; e < end; e += 256) {
        int c = col[e], r = row[e];
        int lpos = atomicAdd(&h[c >> NBITS], 1);
        pk[lpos] = ((unsigned)r << NBITS) | (unsigned)(c & (BK - 1));
    }
    __syncthreads();
    const int tot = lbase[B];
    for (int i = t; i < tot; i += 256) {
        int lo = 0, hi = B - 1;
        while (lo < hi) {
            int mid = (lo + hi + 1) >> 1;
            if (lbase[mid] <= i) lo = mid; else hi = mid - 1;
        }
        pairs[delta[lo] + i] = pk[i];
    }
}

// ---------- per-bucket counting sort by (dst, src-slice) -> CSR segments noffS + dinv ----------
__global__ __launch_bounds__(1024) void k_sort(const unsigned* __restrict__ pairs,
                                               const int* __restrict__ boff,
                                               int* __restrict__ srcs, int* __restrict__ noffS,
                                               float* __restrict__ dinv, int N, float invSlice) {
    __shared__ int cnt[SBINS];
    __shared__ int cur[SBINS];
    const int bb = blockIdx.x;
    const int t = threadIdx.x;
    cnt[t] = 0;   // blockDim == SBINS == 1024
    __syncthreads();
    const int beg = boff[bb], end = boff[bb + 1];
    for (int i = beg + t; i < end; i += 1024) {
        unsigned p = pairs[i];
        int src = (int)(p >> NBITS);
        int s = (int)((float)src * invSlice); if (s > NSLICE - 1) s = NSLICE - 1;
        atomicAdd(&cnt[(((int)p & (BK - 1)) << 2) | s], 1);
    }
    __syncthreads();
    if (t < 64) {
        int carry = 0;
        for (int base = 0; base < SBINS; base += 64) {
            int v = cnt[base + t];
            int inc = v;
            for (int off = 1; off < 64; off <<= 1) {
                int u = __shfl_up(inc, off);
                if (t >= off) inc += u;
            }
            cur[base + t] = beg + carry + inc - v;
            carry += __shfl(inc, 63);
        }
    }
    __syncthreads();
    {   // bin t == local_node*(NSLICE) + slice; write segment start
        int n = bb * BK + (t >> 2);
        if (n < N) noffS[(size_t)n * NSLICE + (t & 3)] = cur[t];
    }
    if (t < BK) {
        int n = bb * BK + t;
        if (n < N) {
            int tot = cnt[(t << 2)] + cnt[(t << 2) | 1] + cnt[(t << 2) | 2] + cnt[(t << 2) | 3];
            dinv[n] = rsqrtf((float)(tot + 1));  // +1 self-loop
        }
    }
    __syncthreads();
    for (int i = beg + t; i < end; i += 1024) {
        unsigned p = pairs[i];
        int src = (int)(p >> NBITS);
        int s = (int)((float)src * invSlice); if (s > NSLICE - 1) s = NSLICE - 1;
        int pos = atomicAdd(&cur[(((int)p & (BK - 1)) << 2) | s], 1);
        srcs[pos] = src;
    }
}

// ---------- GEMM: Y[n,32] = bf16(dinv[n]*(X[n,K]@W[K,32])); optional fused BN+ReLU on X ----------
// W lives in REGISTERS (K=128: half-column per lane + shfl combine; K=32: full column/lane).
// X staged in LDS, read as broadcast float4. Replaces the LDS-pipe-bound 160-reads/row scheme.
template <int K, bool APPLY_BN>
__global__ __launch_bounds__(256) void k_gemm(const float* __restrict__ X,
                                              const float* __restrict__ W,
                                              const float* __restrict__ dinv,
                                              __hip_bfloat16* __restrict__ Y, int n,
                                              const float* __restrict__ stats,
                                              const float* __restrict__ gamma,
                                              const float* __restrict__ beta, float invN) {
    constexpr int ROWS = 64;
    __shared__ __align__(16) float Xs[ROWS * K];   // 32KB (K=128) / 8KB (K=32)
    __shared__ float bnsc[K], bnsh[K];
    const int tid = threadIdx.x;
    const int lane = tid & 63;
    const int w = tid >> 6;
    const int c = lane & 31;
    const int row0 = blockIdx.x * ROWS;

    if (APPLY_BN) {
        if (tid < K) {
            float mean = stats[tid] * invN;
            float var = stats[K + tid] * invN - mean * mean;
            float sc = gamma[tid] * rsqrtf(var + BN_EPS);
            bnsc[tid] = sc;
            bnsh[tid] = beta[tid] - mean * sc;
        }
        __syncthreads();
    }

    // stage W into (front of) Xs, then pull into registers
    for (int i = tid * 4; i < K * HDIM; i += 1024)
        *(float4*)&Xs[i] = *(const float4*)&W[i];
    __syncthreads();
    constexpr int WREG = (K == 128) ? 64 : 32;
    float wreg[WREG];
    if constexpr (K == 128) {
        const int kh = lane >> 5;
#pragma unroll
        for (int kk = 0; kk < 64; ++kk) wreg[kk] = Xs[(kh * 64 + kk) * HDIM + c];
    } else {
#pragma unroll
        for (int kk = 0; kk < 32; ++kk) wreg[kk] = Xs[kk * HDIM + c];
    }
    __syncthreads();

    // stage X rows [row0, row0+64), BN+ReLU fused
    for (int i = tid * 4; i < ROWS * K; i += 1024) {
        int r = i / K, k = i % K;
        int gr = row0 + r;
        float4 v = make_float4(0.f, 0.f, 0.f, 0.f);
        if (gr < n) v = *(const float4*)&X[(size_t)gr * K + k];
        if (APPLY_BN) {
            v.x = fmaxf(v.x * bnsc[k]     + bnsh[k],     0.f);
            v.y = fmaxf(v.y * bnsc[k + 1] + bnsh[k + 1], 0.f);
            v.z = fmaxf(v.z * bnsc[k + 2] + bnsh[k + 2], 0.f);
            v.w = fmaxf(v.w * bnsc[k + 3] + bnsh[k + 3], 0.f);
        }
        *(float4*)&Xs[i] = v;
    }
    __syncthreads();

    if constexpr (K == 128) {
        const int kh = lane >> 5;   // half-wave owns K-half; combine via shfl_xor(32)
        for (int rr = 0; rr < 16; ++rr) {
            const int r = w * 16 + rr;
            float acc = 0.f;
#pragma unroll
            for (int kk = 0; kk < 16; ++kk) {
                float4 xv = *(const float4*)&Xs[r * K + kh * 64 + kk * 4];
                acc += xv.x * wreg[4 * kk]     + xv.y * wreg[4 * kk + 1]
                     + xv.z * wreg[4 * kk + 2] + xv.w * wreg[4 * kk + 3];
            }
            acc += __shfl_xor(acc, 32);
            const int gr = row0 + r;
            if (gr < n && lane < 32)
                Y[(size_t)gr * HDIM + c] = __float2bfloat16(dinv[gr] * acc);
        }
    } else {
        // K=32: half-waves process different rows, no combine
        for (int rr = 0; rr < 8; ++rr) {
            const int r = w * 16 + rr * 2 + (lane >> 5);
            float acc = 0.f;
#pragma unroll
            for (int kk = 0; kk < 8; ++kk) {
                float4 xv = *(const float4*)&Xs[r * K + kk * 4];
                acc += xv.x * wreg[4 * kk]     + xv.y * wreg[4 * kk + 1]
                     + xv.z * wreg[4 * kk + 2] + xv.w * wreg[4 * kk + 3];
            }
            const int gr = row0 + r;
            if (gr < n)
                Y[(size_t)gr * HDIM + c] = __float2bfloat16(dinv[gr] * acc);
        }
    }
}

// bf16 pair unpack via bit ops (no cvt)
__device__ __forceinline__ float blo(unsigned u) { return __uint_as_float(u << 16); }
__device__ __forceinline__ float bhi(unsigned u) { return __uint_as_float(u & 0xffff0000u); }

// ---------- slice-phased gather-aggregate, QUAD-per-node ----------
// Edges sorted by (dst, src-slice). Each quad (4 lanes) owns ONE node; lane p holds
// features [8p,8p+8) via uint4 (16B) gathers. One gather instruction covers 16 edges
// (16 quads) x 16 cache lines -> 2x fewer VMEM instrs and 2x lines-in-flight vs oct/uint2.
// No cross-lane combine needed. Slice phasing keeps the active ~1.6MB table slice in L2.
#define AGG_SLICE(S, BEG, END)                                                \
    {                                                                         \
        int e = (BEG); const int endv = (END);                                \
        if (ss == (S)) {                                                      \
            uint4 u = hp16[(size_t)nb * 4 + p];                               \
            a[0] += blo(u.x); a[1] += bhi(u.x); a[2] += blo(u.y);             \
            a[3] += bhi(u.y); a[4] += blo(u.z); a[5] += bhi(u.z);             \
            a[6] += blo(u.w); a[7] += bhi(u.w);                               \
        }                                                                     \
        for (; e + 7 < endv; e += 8) {                                        \
            int rr[8]; uint4 uu[8];                                           \
            _Pragma("unroll")                                                 \
            for (int k = 0; k < 8; ++k) rr[k] = srcs[e + k];                  \
            _Pragma("unroll")                                                 \
            for (int k = 0; k < 8; ++k) uu[k] = hp16[(size_t)rr[k] * 4 + p];  \
            _Pragma("unroll")                                                 \
            for (int k = 0; k < 8; ++k) {                                     \
                a[0] += blo(uu[k].x); a[1] += bhi(uu[k].x);                   \
                a[2] += blo(uu[k].y); a[3] += bhi(uu[k].y);                   \
                a[4] += blo(uu[k].z); a[5] += bhi(uu[k].z);                   \
                a[6] += blo(uu[k].w); a[7] += bhi(uu[k].w);                   \
            }                                                                 \
        }                                                                     \
        if (e + 3 < endv) {                                                   \
            int rr[4]; uint4 uu[4];                                           \
            _Pragma("unroll")                                                 \
            for (int k = 0; k < 4; ++k) rr[k] = srcs[e + k];                  \
            _Pragma("unroll")                                                 \
            for (int k = 0; k < 4; ++k) uu[k] = hp16[(size_t)rr[k] * 4 + p];  \
            _Pragma("unroll")                                                 \
            for (int k = 0; k < 4; ++k) {                                     \
                a[0] += blo(uu[k].x); a[1] += bhi(uu[k].x);                   \
                a[2] += blo(uu[k].y); a[3] += bhi(uu[k].y);                   \
                a[4] += blo(uu[k].z); a[5] += bhi(uu[k].z);                   \
                a[6] += blo(uu[k].w); a[7] += bhi(uu[k].w);                   \
            }                                                                 \
            e += 4;                                                           \
        }                                                                     \
        for (; e < endv; ++e) {                                               \
            uint4 u = hp16[(size_t)srcs[e] * 4 + p];                          \
            a[0] += blo(u.x); a[1] += bhi(u.x); a[2] += blo(u.y);             \
            a[3] += bhi(u.y); a[4] += blo(u.z); a[5] += bhi(u.z);             \
            a[6] += blo(u.w); a[7] += bhi(u.w);                               \
        }                                                                     \
    }

__global__ __launch_bounds__(256) void k_aggregate(const uint4* __restrict__ hp16,
                                                   const float* __restrict__ dinv,
                                                   const int* __restrict__ noffS,
                                                   const int* __restrict__ srcs,
                                                   const float* __restrict__ bias,
                                                   float* __restrict__ agg,
                                                   float* __restrict__ stats, int N,
                                                   float invSlice) {
    __shared__ float ls[WPB][4][8], lq[WPB][4][8];
    const int tid = threadIdx.x;
    const int lane = tid & 63;
    const int w = tid >> 6;
    const int p = lane & 3;        // 16B chunk -> features [8p, 8p+8)
    const int quad = lane >> 2;    // 0..15, one node per quad
    const int nb = (blockIdx.x * WPB + w) * 16 + quad;

    int o0, o1, o2, o3, o4, ss;
    if (nb < N) {
        int4 o = *(const int4*)&noffS[(size_t)nb * NSLICE];
        o0 = o.x; o1 = o.y; o2 = o.z; o3 = o.w;
        o4 = noffS[(size_t)nb * NSLICE + 4];
        ss = (int)((float)nb * invSlice); if (ss > NSLICE - 1) ss = NSLICE - 1;
    } else { o0 = o1 = o2 = o3 = o4 = 0; ss = -1; }

    float a[8];
#pragma unroll
    for (int j = 0; j < 8; ++j) a[j] = 0.f;

    __syncthreads();
    AGG_SLICE(0, o0, o1);
    __syncthreads();
    AGG_SLICE(1, o1, o2);
    __syncthreads();
    AGG_SLICE(2, o2, o3);
    __syncthreads();
    AGG_SLICE(3, o3, o4);

    // epilogue: bias + dinv, store 32B/lane (quad covers full 128B row), BN stats
    const bool valid = nb < N;
    const float d = valid ? dinv[nb] : 0.f;
    const float4 bA = *(const float4*)&bias[8 * p];
    const float4 bB = *(const float4*)&bias[8 * p + 4];
    float o[8], sv[8], qv[8];
    o[0] = fmaf(d, a[0], bA.x); o[1] = fmaf(d, a[1], bA.y);
    o[2] = fmaf(d, a[2], bA.z); o[3] = fmaf(d, a[3], bA.w);
    o[4] = fmaf(d, a[4], bB.x); o[5] = fmaf(d, a[5], bB.y);
    o[6] = fmaf(d, a[6], bB.z); o[7] = fmaf(d, a[7], bB.w);
#pragma unroll
    for (int j = 0; j < 8; ++j) {
        sv[j] = valid ? o[j] : 0.f;
        qv[j] = valid ? o[j] * o[j] : 0.f;
    }
    if (valid) {
        *(float4*)&agg[(size_t)nb * HDIM + 8 * p]     = make_float4(o[0], o[1], o[2], o[3]);
        *(float4*)&agg[(size_t)nb * HDIM + 8 * p + 4] = make_float4(o[4], o[5], o[6], o[7]);
    }
    // reduce across the 16 quads (xor 4/8/16/32 preserves p)
#pragma unroll
    for (int off = 4; off < 64; off <<= 1) {
#pragma unroll
        for (int j = 0; j < 8; ++j) {
            sv[j] += __shfl_xor(sv[j], off);
            qv[j] += __shfl_xor(qv[j], off);
        }
    }
    if (quad == 0) {
#pragma unroll
        for (int j = 0; j < 8; ++j) { ls[w][p][j] = sv[j]; lq[w][p][j] = qv[j]; }
    }
    __syncthreads();
    if (tid < 32) {
        float A = 0, Bq = 0;
#pragma unroll
        for (int ww = 0; ww < WPB; ++ww) {
            A  += ls[ww][tid >> 3][tid & 7];
            Bq += lq[ww][tid >> 3][tid & 7];
        }
        atomicAdd(&stats[tid], A);
        atomicAdd(&stats[HDIM + tid], Bq);
    }
}

// ---------- final batchnorm apply (layer 2, no relu), float4 ----------
__global__ void k_bnapply(const float* __restrict__ a, const float* __restrict__ stats,
                          const float* __restrict__ gamma, const float* __restrict__ beta,
                          float* __restrict__ out, int n, float invN) {
    int i = (blockIdx.x * 256 + threadIdx.x) * 4;
    if (i < n * HDIM) {
        int j = i & 31;
        float4 v = *(const float4*)&a[i];
        float r[4];
        float* vp = &v.x;
#pragma unroll
        for (int k = 0; k < 4; ++k) {
            float mean = stats[j + k] * invN;
            float var = stats[HDIM + j + k] * invN - mean * mean;
            float g = gamma[j + k] * rsqrtf(var + BN_EPS);
            r[k] = (vp[k] - mean) * g + beta[j + k];
        }
        *(float4*)&out[i] = make_float4(r[0], r[1], r[2], r[3]);
    }
}

extern "C" void kernel_launch(void* const* d_in, const int* in_sizes, int n_in,
                              void* d_out, int out_size, void* d_ws, size_t ws_size,
                              hipStream_t stream) {
    const float* x   = (const float*)d_in[0];
    const int*   ei  = (const int*)d_in[1];
    const float* W1  = (const float*)d_in[2];
    const float* b1  = (const float*)d_in[3];
    const float* g1  = (const float*)d_in[4];
    const float* be1 = (const float*)d_in[5];
    const float* W2  = (const float*)d_in[6];
    const float* b2  = (const float*)d_in[7];
    const float* g2  = (const float*)d_in[8];
    const float* be2 = (const float*)d_in[9];

    const int N = in_sizes[0] / FDIM;
    const int E = in_sizes[1] / 2;
    const int* row = ei;      // source
    const int* col = ei + E;  // target
    const int B = (N + BK - 1) / BK;   // buckets (391 for N=100k, fits BMAX)

    char* p = (char*)d_ws;
    auto alloc = [&](size_t bytes) { char* r = p; p += (bytes + 255) & ~(size_t)255; return r; };
    float*          dinv    = (float*)alloc((size_t)N * 4);
    int*            bcounts = (int*)alloc((size_t)B * 4);
    int*            boff    = (int*)alloc((size_t)(B + 1) * 4);
    int*            bcur    = (int*)alloc((size_t)B * 4);
    int*            noffS   = (int*)alloc(((size_t)N * NSLICE + 1) * 4);
    unsigned*       pairs   = (unsigned*)alloc((size_t)E * 4);
    int*            srcs    = (int*)alloc((size_t)E * 4);
    __hip_bfloat16* B1      = (__hip_bfloat16*)alloc((size_t)N * HDIM * 2);  // hp [N][32] bf16
    float*          B2      = (float*)alloc((size_t)N * HDIM * 4);           // agg (fp32)
    float*          stats   = (float*)alloc(512);  // layer1 [0,64), layer2 [64,128)

    const float invN = 1.0f / (float)N;
    const int sliceSz = (N + NSLICE - 1) / NSLICE;
    const float invSlice = 1.0f / (float)sliceSz;
    const int EBH = (E + CHUNK_H - 1) / CHUNK_H;
    const int EBP = (E + CHUNK_P - 1) / CHUNK_P;
    const int AGG_BLOCKS = (N + WPB * 16 - 1) / (WPB * 16);  // 1563 for N=100k
    const int GEMM_BLOCKS = (N + 63) / 64;

    (void)hipMemsetAsync(bcounts, 0, (size_t)B * 4, stream);
    (void)hipMemsetAsync(stats, 0, 512, stream);

    // bucketed edge partition + per-bucket (dst, src-slice) counting sort -> CSR segments
    k_hist2<<<EBH, 256, 0, stream>>>(col, bcounts, E, B);
    k_bscan<<<1, 256, 0, stream>>>(bcounts, boff, bcur, noffS, B, E, N);
    k_partition<<<EBP, 256, 0, stream>>>(row, col, bcur, pairs, E, B);
    k_sort<<<B, 1024, 0, stream>>>(pairs, boff, srcs, noffS, dinv, N, invSlice);

    // layer 1
    k_gemm<FDIM, false><<<GEMM_BLOCKS, 256, 0, stream>>>(x, W1, dinv, B1, N,
                                                         nullptr, nullptr, nullptr, 0.f);
    k_aggregate<<<AGG_BLOCKS, 256, 0, stream>>>((const uint4*)B1, dinv, noffS, srcs, b1,
                                                B2, stats, N, invSlice);

    // layer 2 (BN1+ReLU fused into gemm2's X load)
    k_gemm<HDIM, true><<<GEMM_BLOCKS, 256, 0, stream>>>(B2, W2, dinv, B1, N,
                                                        stats, g1, be1, invN);
    k_aggregate<<<AGG_BLOCKS, 256, 0, stream>>>((const uint4*)B1, dinv, noffS, srcs, b2,
                                                B2, stats + 2 * HDIM, N, invSlice);
    k_bnapply<<<(N * HDIM / 4 + 255) / 256, 256, 0, stream>>>(B2, stats + 2 * HDIM, g2, be2,
                                                              (float*)d_out, N, invN);
}

// Round 4
// 511.109 us; speedup vs baseline: 1.3693x; 1.0251x over previous
//
#include <hip/hip_runtime.h>
#include <hip/hip_bf16.h>

#define FDIM 128
#define HDIM 32
#define BN_EPS 1e-5f
#define BK 256         // destination nodes per bucket
#define NBITS 8        // log2(BK)
#define CHUNK_H 4096   // edges per hist block
#define CHUNK_P 4096   // edges per partition block
#define BMAX 512       // max buckets (N <= 131072)
#define NSLICE 4       // src slices: ~1.6MB bf16 table slice -> fits per-XCD 4MB L2
#define SBINS (BK * NSLICE)
#define WPB 4          // waves per block; 16 quads/wave, 1 node/quad -> 64 nodes/block

// ---------- per-bucket histogram (LDS) ----------
__global__ void k_hist2(const int* __restrict__ col, int* __restrict__ bcounts, int E, int B) {
    __shared__ int h[BMAX];
    for (int i = threadIdx.x; i < B; i += 256) h[i] = 0;
    __syncthreads();
    int base = blockIdx.x * CHUNK_H;
    int end = min(base + CHUNK_H, E);
    for (int e = base + threadIdx.x; e < end; e += 256)
        atomicAdd(&h[col[e] >> NBITS], 1);
    __syncthreads();
    for (int i = threadIdx.x; i < B; i += 256)
        if (h[i]) atomicAdd(&bcounts[i], h[i]);
}

// ---------- single-block exclusive scan of bucket counts ----------
__global__ void k_bscan(const int* __restrict__ bcounts, int* __restrict__ boff,
                        int* __restrict__ bcur, int* __restrict__ noffS, int B, int E, int N) {
    __shared__ int tsum[256];
    __shared__ int wtot[4];
    const int t = threadIdx.x;
    const int per = (B + 255) / 256;
    const int b0 = t * per;
    int s = 0;
    for (int k = 0; k < per; ++k) { int i = b0 + k; if (i < B) s += bcounts[i]; }
    tsum[t] = s;
    __syncthreads();
    int lane = t & 63, w = t >> 6;
    int v = tsum[t];
    int inc = v;
    for (int off = 1; off < 64; off <<= 1) {
        int u = __shfl_up(inc, off);
        if (lane >= off) inc += u;
    }
    if (lane == 63) wtot[w] = inc;
    __syncthreads();
    int pre = 0;
    for (int k = 0; k < w; ++k) pre += wtot[k];
    int acc = pre + inc - v;  // exclusive prefix
    for (int k = 0; k < per; ++k) {
        int i = b0 + k;
        if (i < B) { boff[i] = acc; bcur[i] = acc; acc += bcounts[i]; }
    }
    if (t == 0) { boff[B] = E; noffS[(size_t)N * NSLICE] = E; }
}

// ---------- partition: single histogram pass (lpos in registers) + pos->bucket LUT ----------
// Replaces the old 2-atomic-pass + 9-step-binary-search scheme. Each thread keeps its 16
// edges' packed value and (bucket,lpos) in registers (unrolled -> compile-time indices),
// so col/row are read ONCE and the scatter loop is 2 coalesced LDS reads per element.
__global__ __launch_bounds__(256) void k_partition(const int* __restrict__ row,
                                                   const int* __restrict__ col,
                                                   int* __restrict__ bcur,
                                                   unsigned* __restrict__ pairs,
                                                   int E, int B) {
    __shared__ int h[BMAX];                 // counts
    __shared__ int lbase[BMAX + 1];         // local exclusive scan
    __shared__ int delta[BMAX];             // global_base - local_base
    __shared__ unsigned pk[CHUNK_P];        // bucket-sorted packed pairs
    __shared__ unsigned short bkt[CHUNK_P]; // position -> bucket id
    const int t = threadIdx.x;
    const int base = blockIdx.x * CHUNK_P;
    const int end = min(base + CHUNK_P, E);

    for (int i = t; i < B; i += 256) h[i] = 0;
    __syncthreads();

    // phase A: one pass — load, pack, histogram; keep (b,lpos) in registers
    unsigned pv[16];
    int bl[16];  // (b << 16) | lpos  (b < 512, lpos < 4096); -1 = invalid
#pragma unroll
    for (int k = 0; k < 16; ++k) {
        const int e = base + t + k * 256;
        pv[k] = 0u; bl[k] = -1;
        if (e < end) {
            int c = col[e], r = row[e];
            int b = c >> NBITS;
            int l = atomicAdd(&h[b], 1);
            pv[k] = ((unsigned)r << NBITS) | (unsigned)(c & (BK - 1));
            bl[k] = (b << 16) | l;
        }
    }
    __syncthreads();

    // phase B: local exclusive scan of bucket counts
    if (t < 64) {
        int carry = 0;
        for (int bb = 0; bb < B; bb += 64) {
            int idx = bb + t;
            int v = (idx < B) ? h[idx] : 0;
            int inc = v;
            for (int off = 1; off < 64; off <<= 1) {
                int u = __shfl_up(inc, off);
                if (t >= off) inc += u;
            }
            if (idx < B) lbase[idx] = carry + inc - v;
            carry += __shfl(inc, 63);
        }
        if (t == 0) lbase[B] = carry;
    }
    __syncthreads();

    // phase C: reserve global ranges
    for (int b = t; b < B; b += 256) {
        int c = h[b];
        if (c) delta[b] = atomicAdd(&bcur[b], c) - lbase[b];
    }
    __syncthreads();

    // phase D: LDS scatter into bucket-sorted order + bucket LUT
#pragma unroll
    for (int k = 0; k < 16; ++k) {
        if (bl[k] >= 0) {
            int b = bl[k] >> 16, l = bl[k] & 0xffff;
            int pos = lbase[b] + l;
            pk[pos] = pv[k];
            bkt[pos] = (unsigned short)b;
        }
    }
    __syncthreads();

    // phase E: coalesced global scatter (LUT lookup instead of binary search)
    const int tot = lbase[B];
    for (int i = t; i < tot; i += 256)
        pairs[delta[bkt[i]] + i] = pk[i];
}

// ---------- per-bucket counting sort by (dst, src-slice) -> CSR segments noffS + dinv ----------
__global__ __launch_bounds__(1024) void k_sort(const unsigned* __restrict__ pairs,
                                               const int* __restrict__ boff,
                                               int* __restrict__ srcs, int* __restrict__ noffS,
                                               float* __restrict__ dinv, int N, float invSlice) {
    __shared__ int cnt[SBINS];
    __shared__ int cur[SBINS];
    const int bb = blockIdx.x;
    const int t = threadIdx.x;
    cnt[t] = 0;   // blockDim == SBINS == 1024
    __syncthreads();
    const int beg = boff[bb], end = boff[bb + 1];
    for (int i = beg + t; i < end; i += 1024) {
        unsigned p = pairs[i];
        int src = (int)(p >> NBITS);
        int s = (int)((float)src * invSlice); if (s > NSLICE - 1) s = NSLICE - 1;
        atomicAdd(&cnt[(((int)p & (BK - 1)) << 2) | s], 1);
    }
    __syncthreads();
    if (t < 64) {
        int carry = 0;
        for (int base = 0; base < SBINS; base += 64) {
            int v = cnt[base + t];
            int inc = v;
            for (int off = 1; off < 64; off <<= 1) {
                int u = __shfl_up(inc, off);
                if (t >= off) inc += u;
            }
            cur[base + t] = beg + carry + inc - v;
            carry += __shfl(inc, 63);
        }
    }
    __syncthreads();
    {   // bin t == local_node*(NSLICE) + slice; write segment start
        int n = bb * BK + (t >> 2);
        if (n < N) noffS[(size_t)n * NSLICE + (t & 3)] = cur[t];
    }
    if (t < BK) {
        int n = bb * BK + t;
        if (n < N) {
            int tot = cnt[(t << 2)] + cnt[(t << 2) | 1] + cnt[(t << 2) | 2] + cnt[(t << 2) | 3];
            dinv[n] = rsqrtf((float)(tot + 1));  // +1 self-loop
        }
    }
    __syncthreads();
    for (int i = beg + t; i < end; i += 1024) {
        unsigned p = pairs[i];
        int src = (int)(p >> NBITS);
        int s = (int)((float)src * invSlice); if (s > NSLICE - 1) s = NSLICE - 1;
        int pos = atomicAdd(&cur[(((int)p & (BK - 1)) << 2) | s], 1);
        srcs[pos] = src;
    }
}

// ---------- GEMM: Y[n,32] = bf16(dinv[n]*(X[n,K]@W[K,32])); optional fused BN+ReLU on X ----------
// W lives in REGISTERS (K=128: half-column per lane + shfl combine; K=32: full column/lane).
// X staged in LDS, read as broadcast float4.
template <int K, bool APPLY_BN>
__global__ __launch_bounds__(256) void k_gemm(const float* __restrict__ X,
                                              const float* __restrict__ W,
                                              const float* __restrict__ dinv,
                                              __hip_bfloat16* __restrict__ Y, int n,
                                              const float* __restrict__ stats,
                                              const float* __restrict__ gamma,
                                              const float* __restrict__ beta, float invN) {
    constexpr int ROWS = 64;
    __shared__ __align__(16) float Xs[ROWS * K];   // 32KB (K=128) / 8KB (K=32)
    __shared__ float bnsc[K], bnsh[K];
    const int tid = threadIdx.x;
    const int lane = tid & 63;
    const int w = tid >> 6;
    const int c = lane & 31;
    const int row0 = blockIdx.x * ROWS;

    if (APPLY_BN) {
        if (tid < K) {
            float mean = stats[tid] * invN;
            float var = stats[K + tid] * invN - mean * mean;
            float sc = gamma[tid] * rsqrtf(var + BN_EPS);
            bnsc[tid] = sc;
            bnsh[tid] = beta[tid] - mean * sc;
        }
        __syncthreads();
    }

    // stage W into (front of) Xs, then pull into registers
    for (int i = tid * 4; i < K * HDIM; i += 1024)
        *(float4*)&Xs[i] = *(const float4*)&W[i];
    __syncthreads();
    constexpr int WREG = (K == 128) ? 64 : 32;
    float wreg[WREG];
    if constexpr (K == 128) {
        const int kh = lane >> 5;
#pragma unroll
        for (int kk = 0; kk < 64; ++kk) wreg[kk] = Xs[(kh * 64 + kk) * HDIM + c];
    } else {
#pragma unroll
        for (int kk = 0; kk < 32; ++kk) wreg[kk] = Xs[kk * HDIM + c];
    }
    __syncthreads();

    // stage X rows [row0, row0+64), BN+ReLU fused
    for (int i = tid * 4; i < ROWS * K; i += 1024) {
        int r = i / K, k = i % K;
        int gr = row0 + r;
        float4 v = make_float4(0.f, 0.f, 0.f, 0.f);
        if (gr < n) v = *(const float4*)&X[(size_t)gr * K + k];
        if (APPLY_BN) {
            v.x = fmaxf(v.x * bnsc[k]     + bnsh[k],     0.f);
            v.y = fmaxf(v.y * bnsc[k + 1] + bnsh[k + 1], 0.f);
            v.z = fmaxf(v.z * bnsc[k + 2] + bnsh[k + 2], 0.f);
            v.w = fmaxf(v.w * bnsc[k + 3] + bnsh[k + 3], 0.f);
        }
        *(float4*)&Xs[i] = v;
    }
    __syncthreads();

    if constexpr (K == 128) {
        const int kh = lane >> 5;   // half-wave owns K-half; combine via shfl_xor(32)
        for (int rr = 0; rr < 16; ++rr) {
            const int r = w * 16 + rr;
            float acc = 0.f;
#pragma unroll
            for (int kk = 0; kk < 16; ++kk) {
                float4 xv = *(const float4*)&Xs[r * K + kh * 64 + kk * 4];
                acc += xv.x * wreg[4 * kk]     + xv.y * wreg[4 * kk + 1]
                     + xv.z * wreg[4 * kk + 2] + xv.w * wreg[4 * kk + 3];
            }
            acc += __shfl_xor(acc, 32);
            const int gr = row0 + r;
            if (gr < n && lane < 32)
                Y[(size_t)gr * HDIM + c] = __float2bfloat16(dinv[gr] * acc);
        }
    } else {
        // K=32: half-waves process different rows, no combine
        for (int rr = 0; rr < 8; ++rr) {
            const int r = w * 16 + rr * 2 + (lane >> 5);
            float acc = 0.f;
#pragma unroll
            for (int kk = 0; kk < 8; ++kk) {
                float4 xv = *(const float4*)&Xs[r * K + kk * 4];
                acc += xv.x * wreg[4 * kk]     + xv.y * wreg[4 * kk + 1]
                     + xv.z * wreg[4 * kk + 2] + xv.w * wreg[4 * kk + 3];
            }
            const int gr = row0 + r;
            if (gr < n)
                Y[(size_t)gr * HDIM + c] = __float2bfloat16(dinv[gr] * acc);
        }
    }
}

// bf16 pair unpack via bit ops (no cvt)
__device__ __forceinline__ float blo(unsigned u) { return __uint_as_float(u << 16); }
__device__ __forceinline__ float bhi(unsigned u) { return __uint_as_float(u & 0xffff0000u); }

// ---------- slice-phased gather-aggregate, QUAD-per-node ----------
#define AGG_SLICE(S, BEG, END)                                                \
    {                                                                         \
        int e = (BEG); const int endv = (END);                                \
        if (ss == (S)) {                                                      \
            uint4 u = hp16[(size_t)nb * 4 + p];                               \
            a[0] += blo(u.x); a[1] += bhi(u.x); a[2] += blo(u.y);             \
            a[3] += bhi(u.y); a[4] += blo(u.z); a[5] += bhi(u.z);             \
            a[6] += blo(u.w); a[7] += bhi(u.w);                               \
        }                                                                     \
        for (; e + 7 < endv; e += 8) {                                        \
            int rr[8]; uint4 uu[8];                                           \
            _Pragma("unroll")                                                 \
            for (int k = 0; k < 8; ++k) rr[k] = srcs[e + k];                  \
            _Pragma("unroll")                                                 \
            for (int k = 0; k < 8; ++k) uu[k] = hp16[(size_t)rr[k] * 4 + p];  \
            _Pragma("unroll")                                                 \
            for (int k = 0; k < 8; ++k) {                                     \
                a[0] += blo(uu[k].x); a[1] += bhi(uu[k].x);                   \
                a[2] += blo(uu[k].y); a[3] += bhi(uu[k].y);                   \
                a[4] += blo(uu[k].z); a[5] += bhi(uu[k].z);                   \
                a[6] += blo(uu[k].w); a[7] += bhi(uu[k].w);                   \
            }                                                                 \
        }                                                                     \
        if (e + 3 < endv) {                                                   \
            int rr[4]; uint4 uu[4];                                           \
            _Pragma("unroll")                                                 \
            for (int k = 0; k < 4; ++k) rr[k] = srcs[e + k];                  \
            _Pragma("unroll")                                                 \
            for (int k = 0; k < 4; ++k) uu[k] = hp16[(size_t)rr[k] * 4 + p];  \
            _Pragma("unroll")                                                 \
            for (int k = 0; k < 4; ++k) {                                     \
                a[0] += blo(uu[k].x); a[1] += bhi(uu[k].x);                   \
                a[2] += blo(uu[k].y); a[3] += bhi(uu[k].y);                   \
                a[4] += blo(uu[k].z); a[5] += bhi(uu[k].z);                   \
                a[6] += blo(uu[k].w); a[7] += bhi(uu[k].w);                   \
            }                                                                 \
            e += 4;                                                           \
        }                                                                     \
        for (; e < endv; ++e) {                                               \
            uint4 u = hp16[(size_t)srcs[e] * 4 + p];                          \
            a[0] += blo(u.x); a[1] += bhi(u.x); a[2] += blo(u.y);             \
            a[3] += bhi(u.y); a[4] += blo(u.z); a[5] += bhi(u.z);             \
            a[6] += blo(u.w); a[7] += bhi(u.w);                               \
        }                                                                     \
    }

__global__ __launch_bounds__(256) void k_aggregate(const uint4* __restrict__ hp16,
                                                   const float* __restrict__ dinv,
                                                   const int* __restrict__ noffS,
                                                   const int* __restrict__ srcs,
                                                   const float* __restrict__ bias,
                                                   float* __restrict__ agg,
                                                   float* __restrict__ stats, int N,
                                                   float invSlice) {
    __shared__ float ls[WPB][4][8], lq[WPB][4][8];
    const int tid = threadIdx.x;
    const int lane = tid & 63;
    const int w = tid >> 6;
    const int p = lane & 3;        // 16B chunk -> features [8p, 8p+8)
    const int quad = lane >> 2;    // 0..15, one node per quad
    const int nb = (blockIdx.x * WPB + w) * 16 + quad;

    int o0, o1, o2, o3, o4, ss;
    if (nb < N) {
        int4 o = *(const int4*)&noffS[(size_t)nb * NSLICE];
        o0 = o.x; o1 = o.y; o2 = o.z; o3 = o.w;
        o4 = noffS[(size_t)nb * NSLICE + 4];
        ss = (int)((float)nb * invSlice); if (ss > NSLICE - 1) ss = NSLICE - 1;
    } else { o0 = o1 = o2 = o3 = o4 = 0; ss = -1; }

    float a[8];
#pragma unroll
    for (int j = 0; j < 8; ++j) a[j] = 0.f;

    __syncthreads();
    AGG_SLICE(0, o0, o1);
    __syncthreads();
    AGG_SLICE(1, o1, o2);
    __syncthreads();
    AGG_SLICE(2, o2, o3);
    __syncthreads();
    AGG_SLICE(3, o3, o4);

    // epilogue: bias + dinv, store 32B/lane (quad covers full 128B row), BN stats
    const bool valid = nb < N;
    const float d = valid ? dinv[nb] : 0.f;
    const float4 bA = *(const float4*)&bias[8 * p];
    const float4 bB = *(const float4*)&bias[8 * p + 4];
    float o[8], sv[8], qv[8];
    o[0] = fmaf(d, a[0], bA.x); o[1] = fmaf(d, a[1], bA.y);
    o[2] = fmaf(d, a[2], bA.z); o[3] = fmaf(d, a[3], bA.w);
    o[4] = fmaf(d, a[4], bB.x); o[5] = fmaf(d, a[5], bB.y);
    o[6] = fmaf(d, a[6], bB.z); o[7] = fmaf(d, a[7], bB.w);
#pragma unroll
    for (int j = 0; j < 8; ++j) {
        sv[j] = valid ? o[j] : 0.f;
        qv[j] = valid ? o[j] * o[j] : 0.f;
    }
    if (valid) {
        *(float4*)&agg[(size_t)nb * HDIM + 8 * p]     = make_float4(o[0], o[1], o[2], o[3]);
        *(float4*)&agg[(size_t)nb * HDIM + 8 * p + 4] = make_float4(o[4], o[5], o[6], o[7]);
    }
    // reduce across the 16 quads (xor 4/8/16/32 preserves p)
#pragma unroll
    for (int off = 4; off < 64; off <<= 1) {
#pragma unroll
        for (int j = 0; j < 8; ++j) {
            sv[j] += __shfl_xor(sv[j], off);
            qv[j] += __shfl_xor(qv[j], off);
        }
    }
    if (quad == 0) {
#pragma unroll
        for (int j = 0; j < 8; ++j) { ls[w][p][j] = sv[j]; lq[w][p][j] = qv[j]; }
    }
    __syncthreads();
    if (tid < 32) {
        float A = 0, Bq = 0;
#pragma unroll
        for (int ww = 0; ww < WPB; ++ww) {
            A  += ls[ww][tid >> 3][tid & 7];
            Bq += lq[ww][tid >> 3][tid & 7];
        }
        atomicAdd(&stats[tid], A);
        atomicAdd(&stats[HDIM + tid], Bq);
    }
}

// ---------- final batchnorm apply (layer 2, no relu), float4 ----------
__global__ void k_bnapply(const float* __restrict__ a, const float* __restrict__ stats,
                          const float* __restrict__ gamma, const float* __restrict__ beta,
                          float* __restrict__ out, int n, float invN) {
    int i = (blockIdx.x * 256 + threadIdx.x) * 4;
    if (i < n * HDIM) {
        int j = i & 31;
        float4 v = *(const float4*)&a[i];
        float r[4];
        float* vp = &v.x;
#pragma unroll
        for (int k = 0; k < 4; ++k) {
            float mean = stats[j + k] * invN;
            float var = stats[HDIM + j + k] * invN - mean * mean;
            float g = gamma[j + k] * rsqrtf(var + BN_EPS);
            r[k] = (vp[k] - mean) * g + beta[j + k];
        }
        *(float4*)&out[i] = make_float4(r[0], r[1], r[2], r[3]);
    }
}

extern "C" void kernel_launch(void* const* d_in, const int* in_sizes, int n_in,
                              void* d_out, int out_size, void* d_ws, size_t ws_size,
                              hipStream_t stream) {
    const float* x   = (const float*)d_in[0];
    const int*   ei  = (const int*)d_in[1];
    const float* W1  = (const float*)d_in[2];
    const float* b1  = (const float*)d_in[3];
    const float* g1  = (const float*)d_in[4];
    const float* be1 = (const float*)d_in[5];
    const float* W2  = (const float*)d_in[6];
    const float* b2  = (const float*)d_in[7];
    const float* g2  = (const float*)d_in[8];
    const float* be2 = (const float*)d_in[9];

    const int N = in_sizes[0] / FDIM;
    const int E = in_sizes[1] / 2;
    const int* row = ei;      // source
    const int* col = ei + E;  // target
    const int B = (N + BK - 1) / BK;   // buckets (391 for N=100k, fits BMAX)

    char* p = (char*)d_ws;
    auto alloc = [&](size_t bytes) { char* r = p; p += (bytes + 255) & ~(size_t)255; return r; };
    float*          dinv    = (float*)alloc((size_t)N * 4);
    int*            bcounts = (int*)alloc((size_t)B * 4);
    int*            boff    = (int*)alloc((size_t)(B + 1) * 4);
    int*            bcur    = (int*)alloc((size_t)B * 4);
    int*            noffS   = (int*)alloc(((size_t)N * NSLICE + 1) * 4);
    unsigned*       pairs   = (unsigned*)alloc((size_t)E * 4);
    int*            srcs    = (int*)alloc((size_t)E * 4);
    __hip_bfloat16* B1      = (__hip_bfloat16*)alloc((size_t)N * HDIM * 2);  // hp [N][32] bf16
    float*          B2      = (float*)alloc((size_t)N * HDIM * 4);           // agg (fp32)
    float*          stats   = (float*)alloc(512);  // layer1 [0,64), layer2 [64,128)

    const float invN = 1.0f / (float)N;
    const int sliceSz = (N + NSLICE - 1) / NSLICE;
    const float invSlice = 1.0f / (float)sliceSz;
    const int EBH = (E + CHUNK_H - 1) / CHUNK_H;
    const int EBP = (E + CHUNK_P - 1) / CHUNK_P;
    const int AGG_BLOCKS = (N + WPB * 16 - 1) / (WPB * 16);  // 1563 for N=100k
    const int GEMM_BLOCKS = (N + 63) / 64;

    (void)hipMemsetAsync(bcounts, 0, (size_t)B * 4, stream);
    (void)hipMemsetAsync(stats, 0, 512, stream);

    // bucketed edge partition + per-bucket (dst, src-slice) counting sort -> CSR segments
    k_hist2<<<EBH, 256, 0, stream>>>(col, bcounts, E, B);
    k_bscan<<<1, 256, 0, stream>>>(bcounts, boff, bcur, noffS, B, E, N);
    k_partition<<<EBP, 256, 0, stream>>>(row, col, bcur, pairs, E, B);
    k_sort<<<B, 1024, 0, stream>>>(pairs, boff, srcs, noffS, dinv, N, invSlice);

    // layer 1
    k_gemm<FDIM, false><<<GEMM_BLOCKS, 256, 0, stream>>>(x, W1, dinv, B1, N,
                                                         nullptr, nullptr, nullptr, 0.f);
    k_aggregate<<<AGG_BLOCKS, 256, 0, stream>>>((const uint4*)B1, dinv, noffS, srcs, b1,
                                                B2, stats, N, invSlice);

    // layer 2 (BN1+ReLU fused into gemm2's X load)
    k_gemm<HDIM, true><<<GEMM_BLOCKS, 256, 0, stream>>>(B2, W2, dinv, B1, N,
                                                        stats, g1, be1, invN);
    k_aggregate<<<AGG_BLOCKS, 256, 0, stream>>>((const uint4*)B1, dinv, noffS, srcs, b2,
                                                B2, stats + 2 * HDIM, N, invSlice);
    k_bnapply<<<(N * HDIM / 4 + 255) / 256, 256, 0, stream>>>(B2, stats + 2 * HDIM, g2, be2,
                                                              (float*)d_out, N, invN);
}